// Round 1
// baseline (1008.854 us; speedup 1.0000x reference)
//
#include <hip/hip_runtime.h>
#include <hip/hip_bf16.h>

#define HDIM 128

// ---------------- CSR build ----------------

__global__ __launch_bounds__(256) void hist_kernel(const int* __restrict__ ei, int E,
                                                   int* __restrict__ deg) {
    int e = blockIdx.x * 256 + threadIdx.x;
    if (e < E) atomicAdd(&deg[ei[E + e]], 1);  // dst = ei[1][e]
}

__global__ __launch_bounds__(256) void scan1_kernel(const int* __restrict__ deg,
                                                    int* __restrict__ rowp,
                                                    int* __restrict__ bsum, int N) {
    __shared__ int s[256];
    int t = threadIdx.x;
    int i = blockIdx.x * 256 + t;
    int v = (i < N) ? deg[i] : 0;
    s[t] = v; __syncthreads();
    for (int off = 1; off < 256; off <<= 1) {
        int x = (t >= off) ? s[t - off] : 0;
        __syncthreads();
        s[t] += x;
        __syncthreads();
    }
    if (i < N) rowp[i] = s[t] - v;           // local exclusive
    if (t == 255) bsum[blockIdx.x] = s[255]; // block total
}

__global__ __launch_bounds__(256) void scan2_kernel(int* __restrict__ bsum, int NB) {
    __shared__ int s[256];
    int t = threadIdx.x;
    int v = (t < NB) ? bsum[t] : 0;
    s[t] = v; __syncthreads();
    for (int off = 1; off < 256; off <<= 1) {
        int x = (t >= off) ? s[t - off] : 0;
        __syncthreads();
        s[t] += x;
        __syncthreads();
    }
    if (t < NB) bsum[t] = s[t] - v;          // exclusive block offsets
}

__global__ __launch_bounds__(256) void scan3_kernel(int* __restrict__ rowp,
                                                    const int* __restrict__ bsum,
                                                    int* __restrict__ cur, int N, int E) {
    int i = blockIdx.x * 256 + threadIdx.x;
    if (i < N) {
        int r = rowp[i] + bsum[blockIdx.x];
        rowp[i] = r;
        cur[i] = r;
    }
    if (i == 0) rowp[N] = E;
}

__global__ __launch_bounds__(256) void scatter_kernel(const int* __restrict__ ei, int E,
                                                      int* __restrict__ cur,
                                                      int* __restrict__ srcs) {
    int e = blockIdx.x * 256 + threadIdx.x;
    if (e < E) {
        int d = ei[E + e];
        int p = atomicAdd(&cur[d], 1);
        srcs[p] = ei[e];  // src = ei[0][e]
    }
}

// ---------------- aggregation: out[i] = h[i] + sum_{j->i} h[j] ----------------
// one wave per node, lane handles 2 consecutive floats (wave reads 512B rows)

__global__ __launch_bounds__(256) void agg_kernel(const float* __restrict__ h,
                                                  const int* __restrict__ rowp,
                                                  const int* __restrict__ srcs,
                                                  float* __restrict__ out, int N) {
    int lane = threadIdx.x & 63;
    int node = blockIdx.x * 4 + (threadIdx.x >> 6);
    if (node >= N) return;
    const float2* h2 = (const float2*)h;
    float2 acc = h2[node * 64 + lane];
    int beg = rowp[node], end = rowp[node + 1];
    for (int p = beg; p < end; ++p) {
        int s = srcs[p];
        float2 v = h2[s * 64 + lane];
        acc.x += v.x;
        acc.y += v.y;
    }
    ((float2*)out)[node * 64 + lane] = acc;
}

// ---------------- GEMM: out = act(in @ W + b), K = 128 ----------------
// block tile ROWS x J; thread computes 4 rows x 4 cols. ACT: 0=relu, 1=sigmoid

template <int J, int ACT>
__global__ __launch_bounds__(256) void gemm_kernel(const float* __restrict__ in,
                                                   const float* __restrict__ W,
                                                   const float* __restrict__ bias,
                                                   float* __restrict__ out, int N) {
    constexpr int TX = J / 4;       // threads along cols
    constexpr int TY = 256 / TX;    // thread-groups along rows
    constexpr int ROWS = TY * 4;    // rows per block
    __shared__ float4 sh[ROWS * 32];  // ROWS x 128 floats

    int tid = threadIdx.x;
    int tx = tid % TX;
    int ty = tid / TX;
    int row0 = blockIdx.x * ROWS;

    const float4* in4 = (const float4*)in;
    for (int i = tid; i < ROWS * 32; i += 256) {
        int r = i >> 5, c = i & 31;
        int row = row0 + r;
        float4 z = {0.f, 0.f, 0.f, 0.f};
        sh[i] = (row < N) ? in4[row * 32 + c] : z;
    }
    __syncthreads();

    const float4* W4 = (const float4*)W;
    float acc[4][4];
#pragma unroll
    for (int r = 0; r < 4; ++r)
#pragma unroll
        for (int c = 0; c < 4; ++c) acc[r][c] = 0.f;

#pragma unroll 8
    for (int kk = 0; kk < 128; kk += 4) {
        float4 w0 = W4[(kk + 0) * TX + tx];
        float4 w1 = W4[(kk + 1) * TX + tx];
        float4 w2 = W4[(kk + 2) * TX + tx];
        float4 w3 = W4[(kk + 3) * TX + tx];
#pragma unroll
        for (int r = 0; r < 4; ++r) {
            float4 hv = sh[(ty * 4 + r) * 32 + (kk >> 2)];
            acc[r][0] += hv.x * w0.x + hv.y * w1.x + hv.z * w2.x + hv.w * w3.x;
            acc[r][1] += hv.x * w0.y + hv.y * w1.y + hv.z * w2.y + hv.w * w3.y;
            acc[r][2] += hv.x * w0.z + hv.y * w1.z + hv.z * w2.z + hv.w * w3.z;
            acc[r][3] += hv.x * w0.w + hv.y * w1.w + hv.z * w2.w + hv.w * w3.w;
        }
    }

    float4 bv = ((const float4*)bias)[tx];
#pragma unroll
    for (int r = 0; r < 4; ++r) {
        int row = row0 + ty * 4 + r;
        if (row < N) {
            float4 v;
            v.x = acc[r][0] + bv.x;
            v.y = acc[r][1] + bv.y;
            v.z = acc[r][2] + bv.z;
            v.w = acc[r][3] + bv.w;
            if (ACT == 0) {
                v.x = fmaxf(v.x, 0.f); v.y = fmaxf(v.y, 0.f);
                v.z = fmaxf(v.z, 0.f); v.w = fmaxf(v.w, 0.f);
            } else {
                v.x = 1.f / (1.f + __expf(-v.x));
                v.y = 1.f / (1.f + __expf(-v.y));
                v.z = 1.f / (1.f + __expf(-v.z));
                v.w = 1.f / (1.f + __expf(-v.w));
            }
            ((float4*)out)[row * TX + tx] = v;
        }
    }
}

// ---------------- orchestration ----------------

extern "C" void kernel_launch(void* const* d_in, const int* in_sizes, int n_in,
                              void* d_out, int out_size, void* d_ws, size_t ws_size,
                              hipStream_t stream) {
    const float* x   = (const float*)d_in[0];
    const int*   ei  = (const int*)d_in[1];
    const float* w0a = (const float*)d_in[2];
    const float* b0a = (const float*)d_in[3];
    const float* w0b = (const float*)d_in[4];
    const float* b0b = (const float*)d_in[5];
    const float* wma = (const float*)d_in[6];
    const float* bma = (const float*)d_in[7];
    const float* wmb = (const float*)d_in[8];
    const float* bmb = (const float*)d_in[9];
    const float* wl  = (const float*)d_in[10];
    const float* bl  = (const float*)d_in[11];

    const int N = in_sizes[0] / HDIM;
    const int E = in_sizes[1] / 2;

    // workspace layout
    float* A = (float*)d_ws;
    float* B = A + (size_t)N * HDIM;
    int* deg  = (int*)(B + (size_t)N * HDIM);
    int* rowp = deg + N;
    int* cur  = rowp + N + 1;
    int* bsum = cur + N;
    int* srcs = bsum + 256;

    const int NB = (N + 255) / 256;
    dim3 blk(256);

    // ---- CSR build (per call; deterministic work) ----
    hipMemsetAsync(deg, 0, (size_t)N * sizeof(int), stream);
    hist_kernel<<<(E + 255) / 256, blk, 0, stream>>>(ei, E, deg);
    scan1_kernel<<<NB, blk, 0, stream>>>(deg, rowp, bsum, N);
    scan2_kernel<<<1, blk, 0, stream>>>(bsum, NB);
    scan3_kernel<<<NB, blk, 0, stream>>>(rowp, bsum, cur, N, E);
    scatter_kernel<<<(E + 255) / 256, blk, 0, stream>>>(ei, E, cur, srcs);

    const int agg_grid  = (N + 3) / 4;
    const int g128_grid = (N + 31) / 32;
    const int g64_grid  = (N + 63) / 64;

    // ---- layer 0 ----
    agg_kernel<<<agg_grid, blk, 0, stream>>>(x, rowp, srcs, A, N);
    gemm_kernel<128, 0><<<g128_grid, blk, 0, stream>>>(A, w0a, b0a, B, N);
    gemm_kernel<128, 0><<<g128_grid, blk, 0, stream>>>(B, w0b, b0b, A, N);

    // ---- middle layers 1..4 ----
    float* h = A;
    float* o = B;
    for (int l = 0; l < 4; ++l) {
        const float* wa = wma + (size_t)l * HDIM * HDIM;
        const float* ba = bma + (size_t)l * HDIM;
        const float* wb = wmb + (size_t)l * HDIM * HDIM;
        const float* bb = bmb + (size_t)l * HDIM;
        agg_kernel<<<agg_grid, blk, 0, stream>>>(h, rowp, srcs, o, N);
        gemm_kernel<128, 0><<<g128_grid, blk, 0, stream>>>(o, wa, ba, h, N);
        gemm_kernel<128, 0><<<g128_grid, blk, 0, stream>>>(h, wb, bb, o, N);
        float* t = h; h = o; o = t;
    }

    // ---- last layer ----
    agg_kernel<<<agg_grid, blk, 0, stream>>>(h, rowp, srcs, o, N);
    gemm_kernel<64, 1><<<g64_grid, blk, 0, stream>>>(o, wl, bl, (float*)d_out, N);
}

// Round 2
// 810.064 us; speedup vs baseline: 1.2454x; 1.2454x over previous
//
#include <hip/hip_runtime.h>
#include <hip/hip_bf16.h>

#define HDIM 128

// ---------------- CSR build ----------------

__global__ __launch_bounds__(256) void hist_kernel(const int* __restrict__ ei, int E,
                                                   int* __restrict__ deg) {
    int e = blockIdx.x * 256 + threadIdx.x;
    if (e < E) atomicAdd(&deg[ei[E + e]], 1);  // dst = ei[1][e]
}

__global__ __launch_bounds__(256) void scan1_kernel(const int* __restrict__ deg,
                                                    int* __restrict__ rowp,
                                                    int* __restrict__ bsum, int N) {
    __shared__ int s[256];
    int t = threadIdx.x;
    int i = blockIdx.x * 256 + t;
    int v = (i < N) ? deg[i] : 0;
    s[t] = v; __syncthreads();
    for (int off = 1; off < 256; off <<= 1) {
        int x = (t >= off) ? s[t - off] : 0;
        __syncthreads();
        s[t] += x;
        __syncthreads();
    }
    if (i < N) rowp[i] = s[t] - v;           // local exclusive
    if (t == 255) bsum[blockIdx.x] = s[255]; // block total
}

__global__ __launch_bounds__(256) void scan2_kernel(int* __restrict__ bsum, int NB) {
    __shared__ int s[256];
    int t = threadIdx.x;
    int v = (t < NB) ? bsum[t] : 0;
    s[t] = v; __syncthreads();
    for (int off = 1; off < 256; off <<= 1) {
        int x = (t >= off) ? s[t - off] : 0;
        __syncthreads();
        s[t] += x;
        __syncthreads();
    }
    if (t < NB) bsum[t] = s[t] - v;          // exclusive block offsets
}

__global__ __launch_bounds__(256) void scan3_kernel(int* __restrict__ rowp,
                                                    const int* __restrict__ bsum,
                                                    int* __restrict__ cur, int N, int E) {
    int i = blockIdx.x * 256 + threadIdx.x;
    if (i < N) {
        int r = rowp[i] + bsum[blockIdx.x];
        rowp[i] = r;
        cur[i] = r;
    }
    if (i == 0) rowp[N] = E;
}

__global__ __launch_bounds__(256) void scatter_kernel(const int* __restrict__ ei, int E,
                                                      int* __restrict__ cur,
                                                      int* __restrict__ srcs) {
    int e = blockIdx.x * 256 + threadIdx.x;
    if (e < E) {
        int d = ei[E + e];
        int p = atomicAdd(&cur[d], 1);
        srcs[p] = ei[e];  // src = ei[0][e]
    }
}

// ---------------- aggregation: out[i] = h[i] + sum_{j->i} h[j] ----------------
// wave per node, lane = 2 floats (512B/row). 4-deep unrolled gather for MLP.

__global__ __launch_bounds__(256) void agg_kernel(const float* __restrict__ h,
                                                  const int* __restrict__ rowp,
                                                  const int* __restrict__ srcs,
                                                  float* __restrict__ out, int N) {
    int lane = threadIdx.x & 63;
    int node = blockIdx.x * 4 + (threadIdx.x >> 6);
    if (node >= N) return;
    const float2* h2 = (const float2*)h;
    int beg = rowp[node], end = rowp[node + 1];
    float2 a0 = h2[node * 64 + lane];
    float2 a1 = {0.f, 0.f}, a2 = {0.f, 0.f}, a3 = {0.f, 0.f};
    int p = beg;
    for (; p + 4 <= end; p += 4) {
        int s0 = srcs[p + 0];
        int s1 = srcs[p + 1];
        int s2 = srcs[p + 2];
        int s3 = srcs[p + 3];
        float2 v0 = h2[s0 * 64 + lane];
        float2 v1 = h2[s1 * 64 + lane];
        float2 v2 = h2[s2 * 64 + lane];
        float2 v3 = h2[s3 * 64 + lane];
        a0.x += v0.x; a0.y += v0.y;
        a1.x += v1.x; a1.y += v1.y;
        a2.x += v2.x; a2.y += v2.y;
        a3.x += v3.x; a3.y += v3.y;
    }
    for (; p < end; ++p) {
        int s = srcs[p];
        float2 v = h2[s * 64 + lane];
        a0.x += v.x; a0.y += v.y;
    }
    a0.x += (a1.x + a2.x) + a3.x;
    a0.y += (a1.y + a2.y) + a3.y;
    ((float2*)out)[node * 64 + lane] = a0;
}

// final-layer: out[i] = sigmoid(t[i] + sum_{j->i} t[j] + bias), t is N x 64
// wave per node, lane = 1 float (256B/row), 4-deep unrolled.

__global__ __launch_bounds__(256) void agg_out_kernel(const float* __restrict__ t,
                                                      const int* __restrict__ rowp,
                                                      const int* __restrict__ srcs,
                                                      const float* __restrict__ bias,
                                                      float* __restrict__ out, int N) {
    int lane = threadIdx.x & 63;
    int node = blockIdx.x * 4 + (threadIdx.x >> 6);
    if (node >= N) return;
    int beg = rowp[node], end = rowp[node + 1];
    float a0 = t[node * 64 + lane];
    float a1 = 0.f, a2 = 0.f, a3 = 0.f;
    int p = beg;
    for (; p + 4 <= end; p += 4) {
        int s0 = srcs[p + 0];
        int s1 = srcs[p + 1];
        int s2 = srcs[p + 2];
        int s3 = srcs[p + 3];
        a0 += t[s0 * 64 + lane];
        a1 += t[s1 * 64 + lane];
        a2 += t[s2 * 64 + lane];
        a3 += t[s3 * 64 + lane];
    }
    for (; p < end; ++p) a0 += t[srcs[p] * 64 + lane];
    float z = a0 + (a1 + a2) + a3 + bias[lane];
    out[node * 64 + lane] = 1.f / (1.f + __expf(-z));
}

// ---------------- GEMM: out = act(in @ W + b), K = 128 ----------------
// block tile (TY*RPT) rows x J cols; thread = RPT rows x 4 cols.
// ACT: 0=relu+bias, 1=sigmoid+bias, 2=none

template <int J, int RPT, int ACT>
__global__ __launch_bounds__(256) void gemm_kernel(const float* __restrict__ in,
                                                   const float* __restrict__ W,
                                                   const float* __restrict__ bias,
                                                   float* __restrict__ out, int N) {
    constexpr int TX = J / 4;        // threads along cols
    constexpr int TY = 256 / TX;     // thread-groups along rows
    constexpr int ROWS = TY * RPT;   // rows per block
    __shared__ float4 sh[ROWS * 32]; // ROWS x 128 floats

    int tid = threadIdx.x;
    int tx = tid % TX;
    int ty = tid / TX;
    int row0 = blockIdx.x * ROWS;

    const float4* in4 = (const float4*)in;
    for (int i = tid; i < ROWS * 32; i += 256) {
        int r = i >> 5, c = i & 31;
        int row = row0 + r;
        float4 z = {0.f, 0.f, 0.f, 0.f};
        sh[i] = (row < N) ? in4[row * 32 + c] : z;
    }
    __syncthreads();

    const float4* W4 = (const float4*)W;
    float acc[RPT][4];
#pragma unroll
    for (int r = 0; r < RPT; ++r)
#pragma unroll
        for (int c = 0; c < 4; ++c) acc[r][c] = 0.f;

#pragma unroll 4
    for (int kk = 0; kk < 128; kk += 4) {
        float4 w0 = W4[(kk + 0) * TX + tx];
        float4 w1 = W4[(kk + 1) * TX + tx];
        float4 w2 = W4[(kk + 2) * TX + tx];
        float4 w3 = W4[(kk + 3) * TX + tx];
#pragma unroll
        for (int r = 0; r < RPT; ++r) {
            float4 hv = sh[(ty * RPT + r) * 32 + (kk >> 2)];
            acc[r][0] += hv.x * w0.x + hv.y * w1.x + hv.z * w2.x + hv.w * w3.x;
            acc[r][1] += hv.x * w0.y + hv.y * w1.y + hv.z * w2.y + hv.w * w3.y;
            acc[r][2] += hv.x * w0.z + hv.y * w1.z + hv.z * w2.z + hv.w * w3.z;
            acc[r][3] += hv.x * w0.w + hv.y * w1.w + hv.z * w2.w + hv.w * w3.w;
        }
    }

    float4 bv = {0.f, 0.f, 0.f, 0.f};
    if (ACT != 2) bv = ((const float4*)bias)[tx];
#pragma unroll
    for (int r = 0; r < RPT; ++r) {
        int row = row0 + ty * RPT + r;
        if (row < N) {
            float4 v;
            v.x = acc[r][0] + bv.x;
            v.y = acc[r][1] + bv.y;
            v.z = acc[r][2] + bv.z;
            v.w = acc[r][3] + bv.w;
            if (ACT == 0) {
                v.x = fmaxf(v.x, 0.f); v.y = fmaxf(v.y, 0.f);
                v.z = fmaxf(v.z, 0.f); v.w = fmaxf(v.w, 0.f);
            } else if (ACT == 1) {
                v.x = 1.f / (1.f + __expf(-v.x));
                v.y = 1.f / (1.f + __expf(-v.y));
                v.z = 1.f / (1.f + __expf(-v.z));
                v.w = 1.f / (1.f + __expf(-v.w));
            }
            ((float4*)out)[row * TX + tx] = v;
        }
    }
}

// ---------------- orchestration ----------------

extern "C" void kernel_launch(void* const* d_in, const int* in_sizes, int n_in,
                              void* d_out, int out_size, void* d_ws, size_t ws_size,
                              hipStream_t stream) {
    const float* x   = (const float*)d_in[0];
    const int*   ei  = (const int*)d_in[1];
    const float* w0a = (const float*)d_in[2];
    const float* b0a = (const float*)d_in[3];
    const float* w0b = (const float*)d_in[4];
    const float* b0b = (const float*)d_in[5];
    const float* wma = (const float*)d_in[6];
    const float* bma = (const float*)d_in[7];
    const float* wmb = (const float*)d_in[8];
    const float* bmb = (const float*)d_in[9];
    const float* wl  = (const float*)d_in[10];
    const float* bl  = (const float*)d_in[11];

    const int N = in_sizes[0] / HDIM;
    const int E = in_sizes[1] / 2;

    // workspace layout
    float* A = (float*)d_ws;
    float* B = A + (size_t)N * HDIM;
    int* deg  = (int*)(B + (size_t)N * HDIM);
    int* rowp = deg + N;
    int* cur  = rowp + N + 1;
    int* bsum = cur + N;
    int* srcs = bsum + 256;

    const int NB = (N + 255) / 256;
    dim3 blk(256);

    // ---- CSR build (per call; deterministic work) ----
    hipMemsetAsync(deg, 0, (size_t)N * sizeof(int), stream);
    hist_kernel<<<(E + 255) / 256, blk, 0, stream>>>(ei, E, deg);
    scan1_kernel<<<NB, blk, 0, stream>>>(deg, rowp, bsum, N);
    scan2_kernel<<<1, blk, 0, stream>>>(bsum, NB);
    scan3_kernel<<<NB, blk, 0, stream>>>(rowp, bsum, cur, N, E);
    scatter_kernel<<<(E + 255) / 256, blk, 0, stream>>>(ei, E, cur, srcs);

    const int agg_grid = (N + 3) / 4;
    const int g64_grid = (N + 63) / 64;   // 64-row tiles

    // ---- layer 0 ----
    agg_kernel<<<agg_grid, blk, 0, stream>>>(x, rowp, srcs, A, N);
    gemm_kernel<128, 8, 0><<<g64_grid, blk, 0, stream>>>(A, w0a, b0a, B, N);
    gemm_kernel<128, 8, 0><<<g64_grid, blk, 0, stream>>>(B, w0b, b0b, A, N);

    // ---- middle layers 1..4 ----
    float* h = A;
    float* o = B;
    for (int l = 0; l < 4; ++l) {
        const float* wa = wma + (size_t)l * HDIM * HDIM;
        const float* ba = bma + (size_t)l * HDIM;
        const float* wb = wmb + (size_t)l * HDIM;
        const float* bb = bmb + (size_t)l * HDIM;
        wb = wmb + (size_t)l * HDIM * HDIM;
        agg_kernel<<<agg_grid, blk, 0, stream>>>(h, rowp, srcs, o, N);
        gemm_kernel<128, 8, 0><<<g64_grid, blk, 0, stream>>>(o, wa, ba, h, N);
        gemm_kernel<128, 8, 0><<<g64_grid, blk, 0, stream>>>(h, wb, bb, o, N);
        float* t = h; h = o; o = t;
    }

    // ---- last layer: t = h @ wl ; out = sigmoid(t + S t + bl) ----
    gemm_kernel<64, 4, 2><<<g64_grid, blk, 0, stream>>>(h, wl, nullptr, o, N);
    agg_out_kernel<<<agg_grid, blk, 0, stream>>>(o, rowp, srcs, bl, (float*)d_out, N);
}